// Round 3
// baseline (19489.293 us; speedup 1.0000x reference)
//
#include <hip/hip_runtime.h>
#include <math.h>

// Problem constants
#define NB 64      // batch
#define NS 128     // seq len
#define ND 1024    // input dim
#define NH 512     // hidden
#define NG 2048    // 4*H
#define NTOT 255   // 2S-1
#define NSTEPS 127 // S-1
#define NWV 511
#define NPV 152

// ws layout (floats):
//  xp   : [2][128][2048][64]  = 33,554,432
//  h_all: [2][128][512][64]   =  8,388,608
//  vec  : [64][255][512]      =  8,355,840
//  bar  : 128 ints
static const size_t XP_SZ  = (size_t)2 * NS * NG * NB;
static const size_t H_SZ   = (size_t)2 * NS * NH * NB;
static const size_t VEC_SZ = (size_t)NB * NTOT * NH;

__device__ __forceinline__ float sigm(float x) { return 1.f / (1.f + __expf(-x)); }

#define FMA4x4(acc, av, bv)                                                    \
  acc[0][0] += av.x * bv.x; acc[0][1] += av.x * bv.y;                          \
  acc[0][2] += av.x * bv.z; acc[0][3] += av.x * bv.w;                          \
  acc[1][0] += av.y * bv.x; acc[1][1] += av.y * bv.y;                          \
  acc[1][2] += av.y * bv.z; acc[1][3] += av.y * bv.w;                          \
  acc[2][0] += av.z * bv.x; acc[2][1] += av.z * bv.y;                          \
  acc[2][2] += av.z * bv.z; acc[2][3] += av.z * bv.w;                          \
  acc[3][0] += av.w * bv.x; acc[3][1] += av.w * bv.y;                          \
  acc[3][2] += av.w * bv.z; acc[3][3] += av.w * bv.w;

// ---------------- K1: xp[dir][t][grow][b] = elmo @ w_ih^T + bias ----------
__global__ __launch_bounds__(256) void k_xp(
    const float* __restrict__ elmo, const float* __restrict__ wf,
    const float* __restrict__ wb, const float* __restrict__ biasf,
    const float* __restrict__ biasb, float* __restrict__ xp,
    int* __restrict__ bar) {
  __shared__ float As[16][68];
  __shared__ float Bs[16][68];
  const int tid = threadIdx.x;
  if (blockIdx.x == 0 && blockIdx.y == 0 && tid < 128) bar[tid] = 0;  // for k_lstm
  const int n0 = blockIdx.x * 64;
  const int t  = blockIdx.y;
  const int lr = tid >> 2, lc4 = (tid & 3) << 2;
  const int tx = tid & 15, ty = tid >> 4;
  float acc[4][4] = {};
  const float* arow = elmo + ((size_t)lr * NS + t) * ND;
  const int n = n0 + lr;
  const float* brow = (n < NG) ? (wf + (size_t)n * ND) : (wb + (size_t)(n - NG) * ND);
  for (int k0 = 0; k0 < ND; k0 += 16) {
    const float4 a4 = *(const float4*)(arow + k0 + lc4);
    As[lc4 + 0][lr] = a4.x; As[lc4 + 1][lr] = a4.y;
    As[lc4 + 2][lr] = a4.z; As[lc4 + 3][lr] = a4.w;
    const float4 b4 = *(const float4*)(brow + k0 + lc4);
    Bs[lc4 + 0][lr] = b4.x; Bs[lc4 + 1][lr] = b4.y;
    Bs[lc4 + 2][lr] = b4.z; Bs[lc4 + 3][lr] = b4.w;
    __syncthreads();
#pragma unroll
    for (int kk = 0; kk < 16; ++kk) {
      const float4 av = *(const float4*)&As[kk][ty << 2];
      const float4 bv = *(const float4*)&Bs[kk][tx << 2];
      FMA4x4(acc, av, bv)
    }
    __syncthreads();
  }
#pragma unroll
  for (int i = 0; i < 4; ++i) {
    const int b = (ty << 2) + i;
#pragma unroll
    for (int j = 0; j < 4; ++j) {
      const int nn = n0 + (tx << 2) + j;
      const int dir = nn >> 11, grow = nn & 2047;
      const float bias = dir ? biasb[grow] : biasf[grow];
      xp[(((size_t)dir * NS + t) * NG + grow) * NB + b] = acc[i][j] + bias;
    }
  }
}

// ---------------- K2: persistent BiLSTM scan, v2 --------------------------
// 256 blocks x 1024 thr (4 waves/SIMD). Block = (dir, 4 cols).
// Thread = (b, q=col-in-4, ks=k-quarter). h_prev staged in LDS fp32 (2 chunks,
// register-pipelined). Gate partials reduced in LDS; 256 update threads hold c.
__global__ __launch_bounds__(1024) void k_lstm(
    const float* __restrict__ whh_f, const float* __restrict__ whh_b,
    const float* __restrict__ xp, float* __restrict__ h_all,
    int* __restrict__ bar) {
  __shared__ float4 Wt4[4][512];      // [q][k] = (w_i,w_f,w_g,w_o)   32 KB
  __shared__ float  hS[256 * 64];     // chunk of h_prev [k_local][b]  64 KB
  __shared__ float  part[4 * 4 * 4 * 64];  // [ks][q][g][b]            16 KB
  const int bid = blockIdx.x;
  const int dir = bid >> 7;
  const int col0 = (bid & 127) << 2;
  const int tid = threadIdx.x;
  const int b = tid & 63, q = (tid >> 6) & 3, ks = tid >> 8;
  const float* whh = dir ? whh_b : whh_f;

  // Load Wt4[q][k].g = whh[(g*NH + col0+q)*NH + k], coalesced in k.
  for (int idx = tid; idx < 8192; idx += 1024) {
    const int k = idx & 511, gq = idx >> 9;
    const int g = gq & 3, qq = gq >> 2;
    ((float*)&Wt4[qq][k])[g] = whh[(size_t)(g * NH + col0 + qq) * NH + k];
  }
  __syncthreads();

  const float* xpd = xp + (size_t)dir * NS * NG * NB;
  float* hd = h_all + (size_t)dir * NS * NH * NB;
  float c = 0.f;  // live only in update threads (tid<256)

  for (int t = 0; t < NS; ++t) {
    const int pos = dir ? (NS - 1 - t) : t;
    // prefetch xp gates for update threads (overlaps staging+compute)
    float x0 = 0.f, x1 = 0.f, x2 = 0.f, x3 = 0.f;
    if (tid < 256) {
      const size_t xbase = (size_t)pos * NG * NB + b;
      const int col = col0 + q;
      x0 = xpd[xbase + (size_t)(0 * NH + col) * NB];
      x1 = xpd[xbase + (size_t)(1 * NH + col) * NB];
      x2 = xpd[xbase + (size_t)(2 * NH + col) * NB];
      x3 = xpd[xbase + (size_t)(3 * NH + col) * NB];
    }
    float a0 = 0.f, a1 = 0.f, a2 = 0.f, a3 = 0.f;
    if (t > 0) {
      const int prevpos = dir ? (NS - t) : (t - 1);
      const float4* hp4 = (const float4*)(hd + (size_t)prevpos * NH * NB);
      float4* hS4 = (float4*)hS;
      // chunk 0: k 0..255  (floats 0..16383 of h_prev slice)
      float4 r0[4], r1[4];
#pragma unroll
      for (int i = 0; i < 4; ++i) r0[i] = hp4[tid + (i << 10)];
#pragma unroll
      for (int i = 0; i < 4; ++i) r1[i] = hp4[4096 + tid + (i << 10)];  // chunk1 in flight
#pragma unroll
      for (int i = 0; i < 4; ++i) hS4[tid + (i << 10)] = r0[i];
      __syncthreads();  // chunk0 staged
      {
        const int klb = ks << 6;  // chunk-local k base
#pragma unroll 8
        for (int i = 0; i < 64; ++i) {
          const float hk = hS[((klb + i) << 6) + b];
          const float4 w = Wt4[q][klb + i];
          a0 += hk * w.x; a1 += hk * w.y; a2 += hk * w.z; a3 += hk * w.w;
        }
      }
      __syncthreads();  // chunk0 consumed
#pragma unroll
      for (int i = 0; i < 4; ++i) hS4[tid + (i << 10)] = r1[i];
      __syncthreads();  // chunk1 staged
      {
        const int klb = ks << 6;
#pragma unroll 8
        for (int i = 0; i < 64; ++i) {
          const float hk = hS[((klb + i) << 6) + b];
          const float4 w = Wt4[q][256 + klb + i];
          a0 += hk * w.x; a1 += hk * w.y; a2 += hk * w.z; a3 += hk * w.w;
        }
      }
      // write partials [ks][q][g][b]
      const int pbase = (((ks << 2) + q) << 2);
      part[((pbase + 0) << 6) + b] = a0;
      part[((pbase + 1) << 6) + b] = a1;
      part[((pbase + 2) << 6) + b] = a2;
      part[((pbase + 3) << 6) + b] = a3;
    }
    __syncthreads();  // partials ready (or t==0: nothing)
    if (tid < 256) {
      float g0 = x0, g1 = x1, g2 = x2, g3 = x3;
      if (t > 0) {
#pragma unroll
        for (int kk = 0; kk < 4; ++kk) {
          const int pb = (((kk << 2) + q) << 2);
          g0 += part[((pb + 0) << 6) + b];
          g1 += part[((pb + 1) << 6) + b];
          g2 += part[((pb + 2) << 6) + b];
          g3 += part[((pb + 3) << 6) + b];
        }
      }
      const float ig = sigm(g0), fg = sigm(g1), og = sigm(g3);
      const float gg = tanhf(g2);
      c = fg * c + ig * gg;
      const float h = og * tanhf(c);
      hd[((size_t)pos * NH + col0 + q) * NB + b] = h;
    }
    if (t < NS - 1) {
      __threadfence();
      __syncthreads();
      if (tid == 0) {
        atomicAdd(&bar[t], 1);
        while (__hip_atomic_load(&bar[t], __ATOMIC_ACQUIRE,
                                 __HIP_MEMORY_SCOPE_AGENT) < 256) {
          __builtin_amdgcn_s_sleep(2);
        }
      }
      __syncthreads();
      __threadfence();
    }
  }
}

// ---------------- K3: combined = lrelu(fwd@W1^T + bwd@W2^T) -> vec --------
__global__ __launch_bounds__(256) void k_comb(
    const float* __restrict__ h_all, const float* __restrict__ W1,
    const float* __restrict__ W2, float* __restrict__ vec) {
  __shared__ float A1[16][68], A2[16][68], B1[16][68], B2[16][68];
  const int tid = threadIdx.x;
  const int n0 = blockIdx.x * 64;
  const int s = blockIdx.y;
  const float* h0 = h_all + (size_t)s * NH * NB;
  const float* h1 = h_all + ((size_t)NS + s) * NH * NB;
  const int aj = tid >> 4, ai4 = (tid & 15) << 2;
  const int lr = tid >> 2, lc4 = (tid & 3) << 2;
  const int tx = tid & 15, ty = tid >> 4;
  const float* b1row = W1 + (size_t)(n0 + lr) * NH;
  const float* b2row = W2 + (size_t)(n0 + lr) * NH;
  float acc[4][4] = {};
  for (int k0 = 0; k0 < NH; k0 += 16) {
    *(float4*)&A1[aj][ai4] = *(const float4*)(h0 + (size_t)(k0 + aj) * NB + ai4);
    *(float4*)&A2[aj][ai4] = *(const float4*)(h1 + (size_t)(k0 + aj) * NB + ai4);
    const float4 w1 = *(const float4*)(b1row + k0 + lc4);
    B1[lc4 + 0][lr] = w1.x; B1[lc4 + 1][lr] = w1.y;
    B1[lc4 + 2][lr] = w1.z; B1[lc4 + 3][lr] = w1.w;
    const float4 w2 = *(const float4*)(b2row + k0 + lc4);
    B2[lc4 + 0][lr] = w2.x; B2[lc4 + 1][lr] = w2.y;
    B2[lc4 + 2][lr] = w2.z; B2[lc4 + 3][lr] = w2.w;
    __syncthreads();
#pragma unroll
    for (int kk = 0; kk < 16; ++kk) {
      const float4 a1 = *(const float4*)&A1[kk][ty << 2];
      const float4 b1 = *(const float4*)&B1[kk][tx << 2];
      FMA4x4(acc, a1, b1)
      const float4 a2 = *(const float4*)&A2[kk][ty << 2];
      const float4 b2 = *(const float4*)&B2[kk][tx << 2];
      FMA4x4(acc, a2, b2)
    }
    __syncthreads();
  }
#pragma unroll
  for (int i = 0; i < 4; ++i) {
    const int b = (ty << 2) + i;
#pragma unroll
    for (int j = 0; j < 4; ++j) {
      const int nn = n0 + (tx << 2) + j;
      float v = acc[i][j];
      v = v > 0.f ? v : 0.01f * v;
      vec[((size_t)b * NTOT + s) * NH + nn] = v;
    }
  }
}

// ---------------- K4: l2-normalize word rows of vec -----------------------
__global__ __launch_bounds__(256) void k_norm(float* __restrict__ vec) {
  const int row = (blockIdx.x << 2) + (threadIdx.x >> 6);  // 0..8191
  const int lane = threadIdx.x & 63;
  const int b = row >> 7, s = row & 127;
  float* p = vec + ((size_t)b * NTOT + s) * NH;
  float4 v0 = *(float4*)(p + (lane << 3));
  float4 v1 = *(float4*)(p + (lane << 3) + 4);
  float ss = v0.x * v0.x + v0.y * v0.y + v0.z * v0.z + v0.w * v0.w +
             v1.x * v1.x + v1.y * v1.y + v1.z * v1.z + v1.w * v1.w;
#pragma unroll
  for (int off = 32; off; off >>= 1) ss += __shfl_down(ss, off);
  ss = __shfl(ss, 0);
  const float sc = 1.f / fmaxf(sqrtf(ss), 1e-12f);
  v0.x *= sc; v0.y *= sc; v0.z *= sc; v0.w *= sc;
  v1.x *= sc; v1.y *= sc; v1.z *= sc; v1.w *= sc;
  *(float4*)(p + (lane << 3)) = v0;
  *(float4*)(p + (lane << 3) + 4) = v1;
}

// ---------------- K5: per-batch tree composition scan ---------------------
__global__ __launch_bounds__(512) void k_compose(
    float* __restrict__ vec, const int* __restrict__ cinfo) {
  __shared__ float lv[512];
  __shared__ float rvd[1028];
  __shared__ float cpart[4][512];
  __shared__ float red[9];
  const int b = blockIdx.x;
  const int tid = threadIdx.x;
  float* vb = vec + (size_t)b * NTOT * NH;
  const int* ib = cinfo + b * NSTEPS * 4;
  const int jq = tid >> 7;
  const int k4 = (tid & 127) << 2;
  const int wid = tid >> 6, lane = tid & 63;
  for (int i = 0; i < NSTEPS; ++i) {
    const int tt = ib[i * 4 + 0], p = ib[i * 4 + 1];
    const int l = ib[i * 4 + 2], r = ib[i * 4 + 3];
    lv[tid] = vb[(size_t)l * NH + tid];
    const float rvv = vb[(size_t)r * NH + tid];
    rvd[tid] = rvv;
    rvd[512 + tid] = rvv;
    __syncthreads();
    float a0 = 0.f, a1 = 0.f, a2 = 0.f, a3 = 0.f;
    if (tt == 2) {
      const int jb = jq << 7;
#pragma unroll 8
      for (int jj = 0; jj < 128; jj += 4) {
        const int j = jb + jj;
        const float4 l4 = *(const float4*)&lv[j];
        const float4 r0 = *(const float4*)&rvd[j + k4];
        const float4 r1 = *(const float4*)&rvd[j + k4 + 4];
        a0 += l4.x * r0.x + l4.y * r0.y + l4.z * r0.z + l4.w * r0.w;
        a1 += l4.x * r0.y + l4.y * r0.z + l4.z * r0.w + l4.w * r1.x;
        a2 += l4.x * r0.z + l4.y * r0.w + l4.z * r1.x + l4.w * r1.y;
        a3 += l4.x * r0.w + l4.y * r1.x + l4.z * r1.y + l4.w * r1.z;
      }
    }
    cpart[jq][k4 + 0] = a0; cpart[jq][k4 + 1] = a1;
    cpart[jq][k4 + 2] = a2; cpart[jq][k4 + 3] = a3;
    __syncthreads();
    const float ck = cpart[0][tid] + cpart[1][tid] + cpart[2][tid] + cpart[3][tid];
    float ss = ck * ck;
#pragma unroll
    for (int off = 32; off; off >>= 1) ss += __shfl_down(ss, off);
    if (lane == 0) red[wid] = ss;
    __syncthreads();
    if (tid == 0) {
      float tot = 0.f;
#pragma unroll
      for (int w = 0; w < 8; ++w) tot += red[w];
      red[8] = 1.f / fmaxf(sqrtf(tot), 1e-12f);
    }
    __syncthreads();
    if (tt == 2) {
      vb[(size_t)p * NH + tid] = ck * red[8];
    } else if (tt == 1) {
      vb[(size_t)p * NH + tid] = lv[tid];
    }
    __syncthreads();
  }
}

// ---------------- K6: output GEMMs (word / phrase) ------------------------
template <int MODE>
__global__ __launch_bounds__(256) void k_out(
    const float* __restrict__ vec, const float* __restrict__ W,
    const float* __restrict__ bias, float* __restrict__ out) {
  constexpr int NOUT = MODE ? NPV : NWV;
  __shared__ float As[16][68], Bs[16][68];
  const int tid = threadIdx.x;
  const int n0 = blockIdx.x * 64, m0 = blockIdx.y * 64;
  const int lr = tid >> 2, lc4 = (tid & 3) << 2;
  const int tx = tid & 15, ty = tid >> 4;
  const int m = m0 + lr;
  int vr;
  if (MODE == 0) {
    vr = (m >> 7) * NTOT + (m & 127);
  } else {
    const int bb = m / 127;
    vr = bb * NTOT + NS + (m - bb * 127);
  }
  const float* arow = vec + (size_t)vr * NH;
  const int n = n0 + lr;
  const float* brow = W + (size_t)n * NH;
  const bool bok = (n < NOUT);
  float acc[4][4] = {};
  for (int k0 = 0; k0 < NH; k0 += 16) {
    const float4 a4 = *(const float4*)(arow + k0 + lc4);
    As[lc4 + 0][lr] = a4.x; As[lc4 + 1][lr] = a4.y;
    As[lc4 + 2][lr] = a4.z; As[lc4 + 3][lr] = a4.w;
    float4 b4 = make_float4(0.f, 0.f, 0.f, 0.f);
    if (bok) b4 = *(const float4*)(brow + k0 + lc4);
    Bs[lc4 + 0][lr] = b4.x; Bs[lc4 + 1][lr] = b4.y;
    Bs[lc4 + 2][lr] = b4.z; Bs[lc4 + 3][lr] = b4.w;
    __syncthreads();
#pragma unroll
    for (int kk = 0; kk < 16; ++kk) {
      const float4 av = *(const float4*)&As[kk][ty << 2];
      const float4 bv = *(const float4*)&Bs[kk][tx << 2];
      FMA4x4(acc, av, bv)
    }
    __syncthreads();
  }
#pragma unroll
  for (int i = 0; i < 4; ++i)
#pragma unroll
    for (int j = 0; j < 4; ++j) {
      const int nn = n0 + (tx << 2) + j;
      if (nn < NOUT)
        out[(size_t)(m0 + (ty << 2) + i) * NOUT + nn] = acc[i][j] + bias[nn];
    }
}

// ---------------- K7: labels (int32 -> f32 copy) --------------------------
__global__ __launch_bounds__(256) void k_labels(
    const int* __restrict__ lab, float* __restrict__ outw,
    float* __restrict__ outp) {
  const int i = blockIdx.x * 256 + threadIdx.x;
  if (i < NB * NS) {
    const int b = i >> 7, s = i & 127;
    outw[i] = (float)lab[b * NTOT + s];
  }
  if (i < NB * NSTEPS) {
    const int b = i / 127;
    outp[i] = (float)lab[b * NTOT + NS + (i - b * 127)];
  }
}

extern "C" void kernel_launch(void* const* d_in, const int* in_sizes, int n_in,
                              void* d_out, int out_size, void* d_ws, size_t ws_size,
                              hipStream_t stream) {
  (void)in_sizes; (void)n_in; (void)out_size; (void)ws_size;
  const float* elmo     = (const float*)d_in[0];
  const float* w_ih_f   = (const float*)d_in[1];
  const float* w_hh_f   = (const float*)d_in[2];
  const float* b_f      = (const float*)d_in[3];
  const float* w_ih_b   = (const float*)d_in[4];
  const float* w_hh_b   = (const float*)d_in[5];
  const float* b_b      = (const float*)d_in[6];
  const float* W1       = (const float*)d_in[7];
  const float* W2       = (const float*)d_in[8];
  const float* word_W   = (const float*)d_in[9];
  const float* word_b   = (const float*)d_in[10];
  const float* phrase_W = (const float*)d_in[11];
  const float* phrase_b = (const float*)d_in[12];
  const int* cinfo      = (const int*)d_in[13];
  const int* lab        = (const int*)d_in[15];

  float* ws    = (float*)d_ws;
  float* xp    = ws;
  float* h_all = xp + XP_SZ;
  float* vec   = h_all + H_SZ;
  int* bar     = (int*)(vec + VEC_SZ);

  float* out_word = (float*)d_out;                       // 8192 x 511
  float* out_phr  = out_word + (size_t)8192 * NWV;       // 8128 x 152
  float* out_lw   = out_phr + (size_t)8128 * NPV;        // 8192
  float* out_lp   = out_lw + 8192;                       // 8128

  k_xp<<<dim3(64, 128), 256, 0, stream>>>(elmo, w_ih_f, w_ih_b, b_f, b_b, xp, bar);
  k_lstm<<<dim3(256), 1024, 0, stream>>>(w_hh_f, w_hh_b, xp, h_all, bar);
  k_comb<<<dim3(8, 128), 256, 0, stream>>>(h_all, W1, W2, vec);
  k_norm<<<dim3(2048), 256, 0, stream>>>(vec);
  k_compose<<<dim3(64), 512, 0, stream>>>(vec, cinfo);
  k_out<0><<<dim3(8, 128), 256, 0, stream>>>(vec, word_W, word_b, out_word);
  k_out<1><<<dim3(3, 127), 256, 0, stream>>>(vec, phrase_W, phrase_b, out_phr);
  k_labels<<<dim3(32), 256, 0, stream>>>(lab, out_lw, out_lp);
}

// Round 4
// 7905.943 us; speedup vs baseline: 2.4651x; 2.4651x over previous
//
#include <hip/hip_runtime.h>
#include <math.h>

// Problem constants
#define NB 64      // batch
#define NS 128     // seq len
#define ND 1024    // input dim
#define NH 512     // hidden
#define NG 2048    // 4*H
#define NTOT 255   // 2S-1
#define NSTEPS 127 // S-1
#define NWV 511
#define NPV 152

static const size_t XP_SZ  = (size_t)2 * NS * NG * NB;
static const size_t H_SZ   = (size_t)2 * NS * NH * NB;
static const size_t VEC_SZ = (size_t)NB * NTOT * NH;

__device__ __forceinline__ float sigm(float x) { return 1.f / (1.f + __expf(-x)); }

#define FMA4x4(acc, av, bv)                                                    \
  acc[0][0] += av.x * bv.x; acc[0][1] += av.x * bv.y;                          \
  acc[0][2] += av.x * bv.z; acc[0][3] += av.x * bv.w;                          \
  acc[1][0] += av.y * bv.x; acc[1][1] += av.y * bv.y;                          \
  acc[1][2] += av.y * bv.z; acc[1][3] += av.y * bv.w;                          \
  acc[2][0] += av.z * bv.x; acc[2][1] += av.z * bv.y;                          \
  acc[2][2] += av.z * bv.z; acc[2][3] += av.z * bv.w;                          \
  acc[3][0] += av.w * bv.x; acc[3][1] += av.w * bv.y;                          \
  acc[3][2] += av.w * bv.z; acc[3][3] += av.w * bv.w;

// ---------------- K1: xp[dir][t][grow][b] = elmo @ w_ih^T + bias ----------
__global__ __launch_bounds__(256) void k_xp(
    const float* __restrict__ elmo, const float* __restrict__ wf,
    const float* __restrict__ wb, const float* __restrict__ biasf,
    const float* __restrict__ biasb, float* __restrict__ xp,
    int* __restrict__ bar) {
  __shared__ float As[16][68];
  __shared__ float Bs[16][68];
  const int tid = threadIdx.x;
  if (blockIdx.x == 0 && blockIdx.y == 0 && tid < 128) bar[tid] = 0;  // for k_lstm
  const int n0 = blockIdx.x * 64;
  const int t  = blockIdx.y;
  const int lr = tid >> 2, lc4 = (tid & 3) << 2;
  const int tx = tid & 15, ty = tid >> 4;
  float acc[4][4] = {};
  const float* arow = elmo + ((size_t)lr * NS + t) * ND;
  const int n = n0 + lr;
  const float* brow = (n < NG) ? (wf + (size_t)n * ND) : (wb + (size_t)(n - NG) * ND);
  for (int k0 = 0; k0 < ND; k0 += 16) {
    const float4 a4 = *(const float4*)(arow + k0 + lc4);
    As[lc4 + 0][lr] = a4.x; As[lc4 + 1][lr] = a4.y;
    As[lc4 + 2][lr] = a4.z; As[lc4 + 3][lr] = a4.w;
    const float4 b4 = *(const float4*)(brow + k0 + lc4);
    Bs[lc4 + 0][lr] = b4.x; Bs[lc4 + 1][lr] = b4.y;
    Bs[lc4 + 2][lr] = b4.z; Bs[lc4 + 3][lr] = b4.w;
    __syncthreads();
#pragma unroll
    for (int kk = 0; kk < 16; ++kk) {
      const float4 av = *(const float4*)&As[kk][ty << 2];
      const float4 bv = *(const float4*)&Bs[kk][tx << 2];
      FMA4x4(acc, av, bv)
    }
    __syncthreads();
  }
#pragma unroll
  for (int i = 0; i < 4; ++i) {
    const int b = (ty << 2) + i;
#pragma unroll
    for (int j = 0; j < 4; ++j) {
      const int nn = n0 + (tx << 2) + j;
      const int dir = nn >> 11, grow = nn & 2047;
      const float bias = dir ? biasb[grow] : biasf[grow];
      xp[(((size_t)dir * NS + t) * NG + grow) * NB + b] = acc[i][j] + bias;
    }
  }
}

// ---------------- K2: persistent BiLSTM scan, v3 --------------------------
// 256 blocks x 256 thr (1 wave/SIMD, all hot reads from LDS).
// Block = (dir, 4 cols). Wave = col q. Lane = (bg, ks): b-group of 4, k-quarter.
// Per k: ds_read_b128 h[k][b4] + ds_read_b128 W(4 gates) -> 16 FMA.
// ks-reduction via in-wave shuffles; no partials buffer; no regs across barriers.
__global__ __launch_bounds__(256) void k_lstm(
    const float* __restrict__ whh_f, const float* __restrict__ whh_b,
    const float* __restrict__ xp, float* __restrict__ h_all,
    int* __restrict__ bar) {
  __shared__ float4 Wt4[4][512];   // [q][slot], slot = k ^ ((k>>7)&3); 32 KB
  __shared__ float  hS[512 * 64];  // [k][b]; 128 KB  (total 160 KB exactly)
  const int bid = blockIdx.x;
  const int dir = bid >> 7;
  const int col0 = (bid & 127) << 2;
  const int tid = threadIdx.x;
  const int lane = tid & 63;
  const int q = tid >> 6;        // wave index = col-in-4
  const int bg = lane & 15;      // b-group (4 consecutive b)
  const int ks = lane >> 4;      // k-quarter (128 k each)
  const float* whh = dir ? whh_b : whh_f;

  // Wt4[qq][k ^ ((k>>7)&3)].g = whh[(g*NH + col0+qq)*NH + k]  (coalesced in k)
  for (int idx = tid; idx < 8192; idx += 256) {
    const int k = idx & 511, gq = idx >> 9;
    const int g = gq & 3, qq = gq >> 2;
    const int slot = k ^ ((k >> 7) & 3);
    ((float*)&Wt4[qq][slot])[g] = whh[(size_t)(g * NH + col0 + qq) * NH + k];
  }
  __syncthreads();

  const float* xpd = xp + (size_t)dir * NS * NG * NB;
  float* hd = h_all + (size_t)dir * NS * NH * NB;
  float4 c4 = make_float4(0.f, 0.f, 0.f, 0.f);  // cell state, lanes<16

  for (int t = 0; t < NS; ++t) {
    const int pos = dir ? (NS - 1 - t) : t;
    // xp prefetch for update lanes (in flight during staging+compute)
    float4 xg0, xg1, xg2, xg3;
    if (lane < 16) {
      const float* xb = xpd + (size_t)pos * NG * NB + (lane << 2);
      xg0 = *(const float4*)(xb + (size_t)(0 * NH + col0 + q) * NB);
      xg1 = *(const float4*)(xb + (size_t)(1 * NH + col0 + q) * NB);
      xg2 = *(const float4*)(xb + (size_t)(2 * NH + col0 + q) * NB);
      xg3 = *(const float4*)(xb + (size_t)(3 * NH + col0 + q) * NB);
    }
    float acc[4][4] = {};  // [gate][j]
    if (t > 0) {
      const int prevpos = dir ? (NS - t) : (t - 1);
      // stage h_prev (128 KB) into LDS; 4-deep batches, no long-lived regs
      const float4* src = (const float4*)(hd + (size_t)prevpos * NH * NB);
      float4* dst = (float4*)hS;
#pragma unroll
      for (int r = 0; r < 8; ++r) {
        const int s0 = ((r << 2) << 8) + tid;
        float4 t0 = src[s0 + 0 * 256];
        float4 t1 = src[s0 + 1 * 256];
        float4 t2 = src[s0 + 2 * 256];
        float4 t3 = src[s0 + 3 * 256];
        dst[s0 + 0 * 256] = t0;
        dst[s0 + 1 * 256] = t1;
        dst[s0 + 2 * 256] = t2;
        dst[s0 + 3 * 256] = t3;
      }
      __syncthreads();
      const int kbase = ks << 7;
#pragma unroll 8
      for (int i = 0; i < 128; ++i) {
        const int k = kbase + i;
        const float4 h4 = *(const float4*)&hS[(k << 6) + (bg << 2)];
        const float4 w4 = Wt4[q][kbase + (i ^ ks)];  // = slot(k)
        FMA4x4(acc, w4, h4)  // acc[g][j] += w4[g] * h4[j]
      }
    }
    // reduce over ks (lane bits 4,5) — all in-wave
#pragma unroll
    for (int g = 0; g < 4; ++g) {
#pragma unroll
      for (int j = 0; j < 4; ++j) {
        acc[g][j] += __shfl_xor(acc[g][j], 16, 64);
        acc[g][j] += __shfl_xor(acc[g][j], 32, 64);
      }
    }
    if (lane < 16) {
      float h0, h1, h2, h3;
      {
        const float gi = xg0.x + acc[0][0], gf = xg1.x + acc[1][0];
        const float gg = xg2.x + acc[2][0], go = xg3.x + acc[3][0];
        c4.x = sigm(gf) * c4.x + sigm(gi) * tanhf(gg);
        h0 = sigm(go) * tanhf(c4.x);
      }
      {
        const float gi = xg0.y + acc[0][1], gf = xg1.y + acc[1][1];
        const float gg = xg2.y + acc[2][1], go = xg3.y + acc[3][1];
        c4.y = sigm(gf) * c4.y + sigm(gi) * tanhf(gg);
        h1 = sigm(go) * tanhf(c4.y);
      }
      {
        const float gi = xg0.z + acc[0][2], gf = xg1.z + acc[1][2];
        const float gg = xg2.z + acc[2][2], go = xg3.z + acc[3][2];
        c4.z = sigm(gf) * c4.z + sigm(gi) * tanhf(gg);
        h2 = sigm(go) * tanhf(c4.z);
      }
      {
        const float gi = xg0.w + acc[0][3], gf = xg1.w + acc[1][3];
        const float gg = xg2.w + acc[2][3], go = xg3.w + acc[3][3];
        c4.w = sigm(gf) * c4.w + sigm(gi) * tanhf(c4.w * 0.f + gg);
        h3 = sigm(go) * tanhf(c4.w);
      }
      *(float4*)(hd + ((size_t)pos * NH + col0 + q) * NB + (lane << 2)) =
          make_float4(h0, h1, h2, h3);
    }
    if (t < NS - 1) {
      __threadfence();           // publish h stores
      __syncthreads();
      if (tid == 0) {
        atomicAdd(&bar[t], 1);
        while (__hip_atomic_load(&bar[t], __ATOMIC_ACQUIRE,
                                 __HIP_MEMORY_SCOPE_AGENT) < 256) {
          __builtin_amdgcn_s_sleep(2);
        }
      }
      __syncthreads();
      __threadfence();           // acquire: no stale h
    }
  }
}

// ---------------- K3: combined = lrelu(fwd@W1^T + bwd@W2^T) -> vec --------
__global__ __launch_bounds__(256) void k_comb(
    const float* __restrict__ h_all, const float* __restrict__ W1,
    const float* __restrict__ W2, float* __restrict__ vec) {
  __shared__ float A1[16][68], A2[16][68], B1[16][68], B2[16][68];
  const int tid = threadIdx.x;
  const int n0 = blockIdx.x * 64;
  const int s = blockIdx.y;
  const float* h0 = h_all + (size_t)s * NH * NB;
  const float* h1 = h_all + ((size_t)NS + s) * NH * NB;
  const int aj = tid >> 4, ai4 = (tid & 15) << 2;
  const int lr = tid >> 2, lc4 = (tid & 3) << 2;
  const int tx = tid & 15, ty = tid >> 4;
  const float* b1row = W1 + (size_t)(n0 + lr) * NH;
  const float* b2row = W2 + (size_t)(n0 + lr) * NH;
  float acc[4][4] = {};
  for (int k0 = 0; k0 < NH; k0 += 16) {
    *(float4*)&A1[aj][ai4] = *(const float4*)(h0 + (size_t)(k0 + aj) * NB + ai4);
    *(float4*)&A2[aj][ai4] = *(const float4*)(h1 + (size_t)(k0 + aj) * NB + ai4);
    const float4 w1 = *(const float4*)(b1row + k0 + lc4);
    B1[lc4 + 0][lr] = w1.x; B1[lc4 + 1][lr] = w1.y;
    B1[lc4 + 2][lr] = w1.z; B1[lc4 + 3][lr] = w1.w;
    const float4 w2 = *(const float4*)(b2row + k0 + lc4);
    B2[lc4 + 0][lr] = w2.x; B2[lc4 + 1][lr] = w2.y;
    B2[lc4 + 2][lr] = w2.z; B2[lc4 + 3][lr] = w2.w;
    __syncthreads();
#pragma unroll
    for (int kk = 0; kk < 16; ++kk) {
      const float4 a1 = *(const float4*)&A1[kk][ty << 2];
      const float4 b1 = *(const float4*)&B1[kk][tx << 2];
      FMA4x4(acc, a1, b1)
      const float4 a2 = *(const float4*)&A2[kk][ty << 2];
      const float4 b2 = *(const float4*)&B2[kk][tx << 2];
      FMA4x4(acc, a2, b2)
    }
    __syncthreads();
  }
#pragma unroll
  for (int i = 0; i < 4; ++i) {
    const int b = (ty << 2) + i;
#pragma unroll
    for (int j = 0; j < 4; ++j) {
      const int nn = n0 + (tx << 2) + j;
      float v = acc[i][j];
      v = v > 0.f ? v : 0.01f * v;
      vec[((size_t)b * NTOT + s) * NH + nn] = v;
    }
  }
}

// ---------------- K4: l2-normalize word rows of vec -----------------------
__global__ __launch_bounds__(256) void k_norm(float* __restrict__ vec) {
  const int row = (blockIdx.x << 2) + (threadIdx.x >> 6);  // 0..8191
  const int lane = threadIdx.x & 63;
  const int b = row >> 7, s = row & 127;
  float* p = vec + ((size_t)b * NTOT + s) * NH;
  float4 v0 = *(float4*)(p + (lane << 3));
  float4 v1 = *(float4*)(p + (lane << 3) + 4);
  float ss = v0.x * v0.x + v0.y * v0.y + v0.z * v0.z + v0.w * v0.w +
             v1.x * v1.x + v1.y * v1.y + v1.z * v1.z + v1.w * v1.w;
#pragma unroll
  for (int off = 32; off; off >>= 1) ss += __shfl_down(ss, off);
  ss = __shfl(ss, 0);
  const float sc = 1.f / fmaxf(sqrtf(ss), 1e-12f);
  v0.x *= sc; v0.y *= sc; v0.z *= sc; v0.w *= sc;
  v1.x *= sc; v1.y *= sc; v1.z *= sc; v1.w *= sc;
  *(float4*)(p + (lane << 3)) = v0;
  *(float4*)(p + (lane << 3) + 4) = v1;
}

// ---------------- K5: per-batch tree composition scan ---------------------
__global__ __launch_bounds__(512) void k_compose(
    float* __restrict__ vec, const int* __restrict__ cinfo) {
  __shared__ float lv[512];
  __shared__ float rvd[1028];
  __shared__ float cpart[4][512];
  __shared__ float red[9];
  const int b = blockIdx.x;
  const int tid = threadIdx.x;
  float* vb = vec + (size_t)b * NTOT * NH;
  const int* ib = cinfo + b * NSTEPS * 4;
  const int jq = tid >> 7;
  const int k4 = (tid & 127) << 2;
  const int wid = tid >> 6, lane = tid & 63;
  for (int i = 0; i < NSTEPS; ++i) {
    const int tt = ib[i * 4 + 0], p = ib[i * 4 + 1];
    const int l = ib[i * 4 + 2], r = ib[i * 4 + 3];
    lv[tid] = vb[(size_t)l * NH + tid];
    const float rvv = vb[(size_t)r * NH + tid];
    rvd[tid] = rvv;
    rvd[512 + tid] = rvv;
    __syncthreads();
    float a0 = 0.f, a1 = 0.f, a2 = 0.f, a3 = 0.f;
    if (tt == 2) {
      const int jb = jq << 7;
#pragma unroll 8
      for (int jj = 0; jj < 128; jj += 4) {
        const int j = jb + jj;
        const float4 l4 = *(const float4*)&lv[j];
        const float4 r0 = *(const float4*)&rvd[j + k4];
        const float4 r1 = *(const float4*)&rvd[j + k4 + 4];
        a0 += l4.x * r0.x + l4.y * r0.y + l4.z * r0.z + l4.w * r0.w;
        a1 += l4.x * r0.y + l4.y * r0.z + l4.z * r0.w + l4.w * r1.x;
        a2 += l4.x * r0.z + l4.y * r0.w + l4.z * r1.x + l4.w * r1.y;
        a3 += l4.x * r0.w + l4.y * r1.x + l4.z * r1.y + l4.w * r1.z;
      }
    }
    cpart[jq][k4 + 0] = a0; cpart[jq][k4 + 1] = a1;
    cpart[jq][k4 + 2] = a2; cpart[jq][k4 + 3] = a3;
    __syncthreads();
    const float ck = cpart[0][tid] + cpart[1][tid] + cpart[2][tid] + cpart[3][tid];
    float ss = ck * ck;
#pragma unroll
    for (int off = 32; off; off >>= 1) ss += __shfl_down(ss, off);
    if (lane == 0) red[wid] = ss;
    __syncthreads();
    if (tid == 0) {
      float tot = 0.f;
#pragma unroll
      for (int w = 0; w < 8; ++w) tot += red[w];
      red[8] = 1.f / fmaxf(sqrtf(tot), 1e-12f);
    }
    __syncthreads();
    if (tt == 2) {
      vb[(size_t)p * NH + tid] = ck * red[8];
    } else if (tt == 1) {
      vb[(size_t)p * NH + tid] = lv[tid];
    }
    __syncthreads();
  }
}

// ---------------- K6: output GEMMs (word / phrase) ------------------------
template <int MODE>
__global__ __launch_bounds__(256) void k_out(
    const float* __restrict__ vec, const float* __restrict__ W,
    const float* __restrict__ bias, float* __restrict__ out) {
  constexpr int NOUT = MODE ? NPV : NWV;
  __shared__ float As[16][68], Bs[16][68];
  const int tid = threadIdx.x;
  const int n0 = blockIdx.x * 64, m0 = blockIdx.y * 64;
  const int lr = tid >> 2, lc4 = (tid & 3) << 2;
  const int tx = tid & 15, ty = tid >> 4;
  const int m = m0 + lr;
  int vr;
  if (MODE == 0) {
    vr = (m >> 7) * NTOT + (m & 127);
  } else {
    const int bb = m / 127;
    vr = bb * NTOT + NS + (m - bb * 127);
  }
  const float* arow = vec + (size_t)vr * NH;
  const int n = n0 + lr;
  const float* brow = W + (size_t)n * NH;
  const bool bok = (n < NOUT);
  float acc[4][4] = {};
  for (int k0 = 0; k0 < NH; k0 += 16) {
    const float4 a4 = *(const float4*)(arow + k0 + lc4);
    As[lc4 + 0][lr] = a4.x; As[lc4 + 1][lr] = a4.y;
    As[lc4 + 2][lr] = a4.z; As[lc4 + 3][lr] = a4.w;
    float4 b4 = make_float4(0.f, 0.f, 0.f, 0.f);
    if (bok) b4 = *(const float4*)(brow + k0 + lc4);
    Bs[lc4 + 0][lr] = b4.x; Bs[lc4 + 1][lr] = b4.y;
    Bs[lc4 + 2][lr] = b4.z; Bs[lc4 + 3][lr] = b4.w;
    __syncthreads();
#pragma unroll
    for (int kk = 0; kk < 16; ++kk) {
      const float4 av = *(const float4*)&As[kk][ty << 2];
      const float4 bv = *(const float4*)&Bs[kk][tx << 2];
      FMA4x4(acc, av, bv)
    }
    __syncthreads();
  }
#pragma unroll
  for (int i = 0; i < 4; ++i)
#pragma unroll
    for (int j = 0; j < 4; ++j) {
      const int nn = n0 + (tx << 2) + j;
      if (nn < NOUT)
        out[(size_t)(m0 + (ty << 2) + i) * NOUT + nn] = acc[i][j] + bias[nn];
    }
}

// ---------------- K7: labels (int32 -> f32 copy) --------------------------
__global__ __launch_bounds__(256) void k_labels(
    const int* __restrict__ lab, float* __restrict__ outw,
    float* __restrict__ outp) {
  const int i = blockIdx.x * 256 + threadIdx.x;
  if (i < NB * NS) {
    const int b = i >> 7, s = i & 127;
    outw[i] = (float)lab[b * NTOT + s];
  }
  if (i < NB * NSTEPS) {
    const int b = i / 127;
    outp[i] = (float)lab[b * NTOT + NS + (i - b * 127)];
  }
}

extern "C" void kernel_launch(void* const* d_in, const int* in_sizes, int n_in,
                              void* d_out, int out_size, void* d_ws, size_t ws_size,
                              hipStream_t stream) {
  (void)in_sizes; (void)n_in; (void)out_size; (void)ws_size;
  const float* elmo     = (const float*)d_in[0];
  const float* w_ih_f   = (const float*)d_in[1];
  const float* w_hh_f   = (const float*)d_in[2];
  const float* b_f      = (const float*)d_in[3];
  const float* w_ih_b   = (const float*)d_in[4];
  const float* w_hh_b   = (const float*)d_in[5];
  const float* b_b      = (const float*)d_in[6];
  const float* W1       = (const float*)d_in[7];
  const float* W2       = (const float*)d_in[8];
  const float* word_W   = (const float*)d_in[9];
  const float* word_b   = (const float*)d_in[10];
  const float* phrase_W = (const float*)d_in[11];
  const float* phrase_b = (const float*)d_in[12];
  const int* cinfo      = (const int*)d_in[13];
  const int* lab        = (const int*)d_in[15];

  float* ws    = (float*)d_ws;
  float* xp    = ws;
  float* h_all = xp + XP_SZ;
  float* vec   = h_all + H_SZ;
  int* bar     = (int*)(vec + VEC_SZ);

  float* out_word = (float*)d_out;                       // 8192 x 511
  float* out_phr  = out_word + (size_t)8192 * NWV;       // 8128 x 152
  float* out_lw   = out_phr + (size_t)8128 * NPV;        // 8192
  float* out_lp   = out_lw + 8192;                       // 8128

  k_xp<<<dim3(64, 128), 256, 0, stream>>>(elmo, w_ih_f, w_ih_b, b_f, b_b, xp, bar);
  k_lstm<<<dim3(256), 256, 0, stream>>>(w_hh_f, w_hh_b, xp, h_all, bar);
  k_comb<<<dim3(8, 128), 256, 0, stream>>>(h_all, W1, W2, vec);
  k_norm<<<dim3(2048), 256, 0, stream>>>(vec);
  k_compose<<<dim3(64), 512, 0, stream>>>(vec, cinfo);
  k_out<0><<<dim3(8, 128), 256, 0, stream>>>(vec, word_W, word_b, out_word);
  k_out<1><<<dim3(3, 127), 256, 0, stream>>>(vec, phrase_W, phrase_b, out_phr);
  k_labels<<<dim3(32), 256, 0, stream>>>(lab, out_lw, out_lp);
}

// Round 5
// 3999.578 us; speedup vs baseline: 4.8728x; 1.9767x over previous
//
#include <hip/hip_runtime.h>
#include <math.h>

// Problem constants
#define NB 64      // batch
#define NS 128     // seq len
#define ND 1024    // input dim
#define NH 512     // hidden
#define NG 2048    // 4*H
#define NTOT 255   // 2S-1
#define NSTEPS 127 // S-1
#define NWV 511
#define NPV 152

static const size_t XP_SZ  = (size_t)2 * NS * NG * NB;                 // floats
static const size_t H_SZ   = (size_t)2 * NS * NH * NB;                 // floats
static const size_t VEC_SZ = (size_t)NB * NTOT * NH;                   // floats
static const size_t HB_SZ  = (size_t)2 * NS * NH * NB;                 // ushorts

typedef __attribute__((ext_vector_type(8))) short short8v;
typedef __attribute__((ext_vector_type(8))) unsigned short ushort8v;
typedef __attribute__((ext_vector_type(4))) float float4v;

__device__ __forceinline__ float sigm(float x) { return 1.f / (1.f + __expf(-x)); }

__device__ __forceinline__ unsigned short f2bf(float x) {
  unsigned b = __float_as_uint(x);
  return (unsigned short)((b + 0x7FFFu + ((b >> 16) & 1u)) >> 16);
}

#define FMA4x4(acc, av, bv)                                                    \
  acc[0][0] += av.x * bv.x; acc[0][1] += av.x * bv.y;                          \
  acc[0][2] += av.x * bv.z; acc[0][3] += av.x * bv.w;                          \
  acc[1][0] += av.y * bv.x; acc[1][1] += av.y * bv.y;                          \
  acc[1][2] += av.y * bv.z; acc[1][3] += av.y * bv.w;                          \
  acc[2][0] += av.z * bv.x; acc[2][1] += av.z * bv.y;                          \
  acc[2][2] += av.z * bv.z; acc[2][3] += av.z * bv.w;                          \
  acc[3][0] += av.w * bv.x; acc[3][1] += av.w * bv.y;                          \
  acc[3][2] += av.w * bv.z; acc[3][3] += av.w * bv.w;

// ---------------- K1: xp[dir][t][grow][b] = elmo @ w_ih^T + bias ----------
__global__ __launch_bounds__(256) void k_xp(
    const float* __restrict__ elmo, const float* __restrict__ wf,
    const float* __restrict__ wb, const float* __restrict__ biasf,
    const float* __restrict__ biasb, float* __restrict__ xp,
    int* __restrict__ bar) {
  __shared__ float As[16][68];
  __shared__ float Bs[16][68];
  const int tid = threadIdx.x;
  // zero the 8192-int barrier array (32 blocks x 256 thr)
  if (blockIdx.x == 0 && blockIdx.y < 32) bar[blockIdx.y * 256 + tid] = 0;
  const int n0 = blockIdx.x * 64;
  const int t  = blockIdx.y;
  const int lr = tid >> 2, lc4 = (tid & 3) << 2;
  const int tx = tid & 15, ty = tid >> 4;
  float acc[4][4] = {};
  const float* arow = elmo + ((size_t)lr * NS + t) * ND;
  const int n = n0 + lr;
  const float* brow = (n < NG) ? (wf + (size_t)n * ND) : (wb + (size_t)(n - NG) * ND);
  for (int k0 = 0; k0 < ND; k0 += 16) {
    const float4 a4 = *(const float4*)(arow + k0 + lc4);
    As[lc4 + 0][lr] = a4.x; As[lc4 + 1][lr] = a4.y;
    As[lc4 + 2][lr] = a4.z; As[lc4 + 3][lr] = a4.w;
    const float4 b4 = *(const float4*)(brow + k0 + lc4);
    Bs[lc4 + 0][lr] = b4.x; Bs[lc4 + 1][lr] = b4.y;
    Bs[lc4 + 2][lr] = b4.z; Bs[lc4 + 3][lr] = b4.w;
    __syncthreads();
#pragma unroll
    for (int kk = 0; kk < 16; ++kk) {
      const float4 av = *(const float4*)&As[kk][ty << 2];
      const float4 bv = *(const float4*)&Bs[kk][tx << 2];
      FMA4x4(acc, av, bv)
    }
    __syncthreads();
  }
#pragma unroll
  for (int i = 0; i < 4; ++i) {
    const int b = (ty << 2) + i;
#pragma unroll
    for (int j = 0; j < 4; ++j) {
      const int nn = n0 + (tx << 2) + j;
      const int dir = nn >> 11, grow = nn & 2047;
      const float bias = dir ? biasb[grow] : biasf[grow];
      xp[(((size_t)dir * NS + t) * NG + grow) * NB + b] = acc[i][j] + bias;
    }
  }
}

// ---------------- K2: persistent BiLSTM scan, v4 (MFMA) -------------------
// 64 blocks = 2 dirs x 32. Block = 16 cols. 256 thr = 4 waves.
// W slice bf16 in LDS [gr=4gate*16col][k] swizzled; h exchanged as bf16.
// Per step: stage h_prev bf16 -> LDS [b][k] swizzled; 256 MFMA 16x16x32;
// C frag: col=lane&15 -> (gate-col), row=(lane>>4)*4+i -> b. c-state f32x4/lane.
// Per-(dir,t) padded barrier counters, 32 participants.
__global__ __launch_bounds__(256) void k_lstm(
    const float* __restrict__ whh_f, const float* __restrict__ whh_b,
    const float* __restrict__ xp, float* __restrict__ h_all,
    unsigned short* __restrict__ h_bf, int* __restrict__ bar) {
  __shared__ unsigned short WS[64 * 512];  // [gr][k] bf16 swizzled, 64 KB
  __shared__ unsigned short hS[64 * 512];  // [b][k]  bf16 swizzled, 64 KB
  const int bid = blockIdx.x;
  const int dir = bid >> 5;
  const int col0 = (bid & 31) << 4;   // 16 cols per block
  const int tid = threadIdx.x;
  const int lane = tid & 63;
  const int w = tid >> 6;             // wave = M-tile (16 b)
  const int cl = lane & 15;           // col_local = C col (n)
  const int bq = lane >> 4;           // b-quad within M-tile
  const int bloc = (w << 4) + (bq << 2);  // C rows: b = bloc..bloc+3
  const float* whh = dir ? whh_b : whh_f;

  // ---- one-time: W slice fp32 -> bf16, swizzled [gr][k] ----
  for (int it = 0; it < 16; ++it) {
    const int lin = it * 256 + tid;   // 4096 chunks of 8 k
    const int gr = lin >> 6;          // 0..63 = gate*16 + col_local
    const int kc = (lin & 63) << 3;   // k chunk base
    const int g = gr >> 4, ccl = gr & 15;
    const float* src = whh + (size_t)(g * NH + col0 + ccl) * NH + kc;
    const float4 f0 = *(const float4*)(src);
    const float4 f1 = *(const float4*)(src + 4);
    ushort8v u;
    u[0] = f2bf(f0.x); u[1] = f2bf(f0.y); u[2] = f2bf(f0.z); u[3] = f2bf(f0.w);
    u[4] = f2bf(f1.x); u[5] = f2bf(f1.y); u[6] = f2bf(f1.z); u[7] = f2bf(f1.w);
    *(ushort8v*)&WS[((gr << 9) + kc) ^ ((gr & 7) << 3)] = u;
  }
  __syncthreads();

  const float* xpd = xp + (size_t)dir * NS * NG * NB;
  float* hd = h_all + (size_t)dir * NS * NH * NB;
  unsigned short* hb = h_bf + (size_t)dir * NS * NH * NB;
  const int col = col0 + cl;
  float4v c4 = {0.f, 0.f, 0.f, 0.f};

  for (int t = 0; t < NS; ++t) {
    const int pos = dir ? (NS - 1 - t) : t;
    // xp prefetch: 4 gates x float4(b) -- issued early, consumed after MFMA
    const float* xb = xpd + (size_t)pos * NG * NB + bloc;
    const float4 xg0 = *(const float4*)(xb + (size_t)(0 * NH + col) * NB);
    const float4 xg1 = *(const float4*)(xb + (size_t)(1 * NH + col) * NB);
    const float4 xg2 = *(const float4*)(xb + (size_t)(2 * NH + col) * NB);
    const float4 xg3 = *(const float4*)(xb + (size_t)(3 * NH + col) * NB);
    float4v acc0 = {0.f, 0.f, 0.f, 0.f}, acc1 = {0.f, 0.f, 0.f, 0.f};
    float4v acc2 = {0.f, 0.f, 0.f, 0.f}, acc3 = {0.f, 0.f, 0.f, 0.f};
    if (t > 0) {
      const int prevpos = dir ? (pos + 1) : (pos - 1);
      // stage h_prev bf16 [b][k] -> LDS swizzled (coalesced 16B/lane)
      const unsigned short* hsrc = hb + (size_t)prevpos * NH * NB;
      const int kl8 = (tid & 63) << 3;
      const int bg = tid >> 6;
#pragma unroll
      for (int i = 0; i < 16; ++i) {
        const int b = (bg << 4) + i;
        const ushort8v v = *(const ushort8v*)(hsrc + ((size_t)b << 9) + kl8);
        *(ushort8v*)&hS[((b << 9) + kl8) ^ ((b & 7) << 3)] = v;
      }
      __syncthreads();
      // MFMA: C[b 0..63][gr 0..63] = h @ W^T, K=512
      const int arow = (w << 4) + cl;   // A-frag row (b)
      const int kofs = bq << 3;
      const int asw = (arow & 7) << 3, bsw = (cl & 7) << 3;
#pragma unroll
      for (int ks = 0; ks < 16; ++ks) {
        const int k0 = (ks << 5) + kofs;
        const short8v a = *(const short8v*)&hS[((arow << 9) + k0) ^ asw];
        const short8v b0 = *(const short8v*)&WS[(((0 * 16 + cl) << 9) + k0) ^ bsw];
        acc0 = __builtin_amdgcn_mfma_f32_16x16x32_bf16(a, b0, acc0, 0, 0, 0);
        const short8v b1 = *(const short8v*)&WS[(((1 * 16 + cl) << 9) + k0) ^ bsw];
        acc1 = __builtin_amdgcn_mfma_f32_16x16x32_bf16(a, b1, acc1, 0, 0, 0);
        const short8v b2 = *(const short8v*)&WS[(((2 * 16 + cl) << 9) + k0) ^ bsw];
        acc2 = __builtin_amdgcn_mfma_f32_16x16x32_bf16(a, b2, acc2, 0, 0, 0);
        const short8v b3 = *(const short8v*)&WS[(((3 * 16 + cl) << 9) + k0) ^ bsw];
        acc3 = __builtin_amdgcn_mfma_f32_16x16x32_bf16(a, b3, acc3, 0, 0, 0);
      }
    }
    // nonlinearity + cell update (fp32 exact)
    float hv[4];
#pragma unroll
    for (int i = 0; i < 4; ++i) {
      const float gi = sigm(acc0[i] + ((const float*)&xg0)[i]);
      const float gf = sigm(acc1[i] + ((const float*)&xg1)[i]);
      const float gg = tanhf(acc2[i] + ((const float*)&xg2)[i]);
      const float go = sigm(acc3[i] + ((const float*)&xg3)[i]);
      c4[i] = gf * c4[i] + gi * gg;
      hv[i] = go * tanhf(c4[i]);
    }
    // store h: fp32 [pos][col][b] for k_comb; bf16 [pos][b][col] for exchange
    *(float4*)(hd + ((size_t)pos * NH + col) * NB + bloc) =
        make_float4(hv[0], hv[1], hv[2], hv[3]);
    unsigned short* hbp = hb + (size_t)pos * NH * NB;
#pragma unroll
    for (int i = 0; i < 4; ++i) hbp[((size_t)(bloc + i) << 9) + col] = f2bf(hv[i]);
    if (t < NS - 1) {
      __threadfence();
      __syncthreads();
      if (tid == 0) {
        int* ctr = &bar[(((t << 1) + dir) << 5)];  // padded 128B apart
        atomicAdd(ctr, 1);
        while (__hip_atomic_load(ctr, __ATOMIC_ACQUIRE,
                                 __HIP_MEMORY_SCOPE_AGENT) < 32) {
          __builtin_amdgcn_s_sleep(1);
        }
      }
      __syncthreads();
      __threadfence();
    } else {
      __syncthreads();
    }
  }
}

// ---------------- K3: combined = lrelu(fwd@W1^T + bwd@W2^T) -> vec --------
__global__ __launch_bounds__(256) void k_comb(
    const float* __restrict__ h_all, const float* __restrict__ W1,
    const float* __restrict__ W2, float* __restrict__ vec) {
  __shared__ float A1[16][68], A2[16][68], B1[16][68], B2[16][68];
  const int tid = threadIdx.x;
  const int n0 = blockIdx.x * 64;
  const int s = blockIdx.y;
  const float* h0 = h_all + (size_t)s * NH * NB;
  const float* h1 = h_all + ((size_t)NS + s) * NH * NB;
  const int aj = tid >> 4, ai4 = (tid & 15) << 2;
  const int lr = tid >> 2, lc4 = (tid & 3) << 2;
  const int tx = tid & 15, ty = tid >> 4;
  const float* b1row = W1 + (size_t)(n0 + lr) * NH;
  const float* b2row = W2 + (size_t)(n0 + lr) * NH;
  float acc[4][4] = {};
  for (int k0 = 0; k0 < NH; k0 += 16) {
    *(float4*)&A1[aj][ai4] = *(const float4*)(h0 + (size_t)(k0 + aj) * NB + ai4);
    *(float4*)&A2[aj][ai4] = *(const float4*)(h1 + (size_t)(k0 + aj) * NB + ai4);
    const float4 w1 = *(const float4*)(b1row + k0 + lc4);
    B1[lc4 + 0][lr] = w1.x; B1[lc4 + 1][lr] = w1.y;
    B1[lc4 + 2][lr] = w1.z; B1[lc4 + 3][lr] = w1.w;
    const float4 w2 = *(const float4*)(b2row + k0 + lc4);
    B2[lc4 + 0][lr] = w2.x; B2[lc4 + 1][lr] = w2.y;
    B2[lc4 + 2][lr] = w2.z; B2[lc4 + 3][lr] = w2.w;
    __syncthreads();
#pragma unroll
    for (int kk = 0; kk < 16; ++kk) {
      const float4 a1 = *(const float4*)&A1[kk][ty << 2];
      const float4 b1 = *(const float4*)&B1[kk][tx << 2];
      FMA4x4(acc, a1, b1)
      const float4 a2 = *(const float4*)&A2[kk][ty << 2];
      const float4 b2 = *(const float4*)&B2[kk][tx << 2];
      FMA4x4(acc, a2, b2)
    }
    __syncthreads();
  }
#pragma unroll
  for (int i = 0; i < 4; ++i) {
    const int b = (ty << 2) + i;
#pragma unroll
    for (int j = 0; j < 4; ++j) {
      const int nn = n0 + (tx << 2) + j;
      float v = acc[i][j];
      v = v > 0.f ? v : 0.01f * v;
      vec[((size_t)b * NTOT + s) * NH + nn] = v;
    }
  }
}

// ---------------- K4: l2-normalize word rows of vec -----------------------
__global__ __launch_bounds__(256) void k_norm(float* __restrict__ vec) {
  const int row = (blockIdx.x << 2) + (threadIdx.x >> 6);  // 0..8191
  const int lane = threadIdx.x & 63;
  const int b = row >> 7, s = row & 127;
  float* p = vec + ((size_t)b * NTOT + s) * NH;
  float4 v0 = *(float4*)(p + (lane << 3));
  float4 v1 = *(float4*)(p + (lane << 3) + 4);
  float ss = v0.x * v0.x + v0.y * v0.y + v0.z * v0.z + v0.w * v0.w +
             v1.x * v1.x + v1.y * v1.y + v1.z * v1.z + v1.w * v1.w;
#pragma unroll
  for (int off = 32; off; off >>= 1) ss += __shfl_down(ss, off);
  ss = __shfl(ss, 0);
  const float sc = 1.f / fmaxf(sqrtf(ss), 1e-12f);
  v0.x *= sc; v0.y *= sc; v0.z *= sc; v0.w *= sc;
  v1.x *= sc; v1.y *= sc; v1.z *= sc; v1.w *= sc;
  *(float4*)(p + (lane << 3)) = v0;
  *(float4*)(p + (lane << 3) + 4) = v1;
}

// ---------------- K5: per-batch tree composition scan ---------------------
__global__ __launch_bounds__(512) void k_compose(
    float* __restrict__ vec, const int* __restrict__ cinfo) {
  __shared__ float lv[512];
  __shared__ float rvd[1028];
  __shared__ float cpart[4][512];
  __shared__ float red[9];
  const int b = blockIdx.x;
  const int tid = threadIdx.x;
  float* vb = vec + (size_t)b * NTOT * NH;
  const int* ib = cinfo + b * NSTEPS * 4;
  const int jq = tid >> 7;
  const int k4 = (tid & 127) << 2;
  const int wid = tid >> 6, lane = tid & 63;
  for (int i = 0; i < NSTEPS; ++i) {
    const int tt = ib[i * 4 + 0], p = ib[i * 4 + 1];
    const int l = ib[i * 4 + 2], r = ib[i * 4 + 3];
    lv[tid] = vb[(size_t)l * NH + tid];
    const float rvv = vb[(size_t)r * NH + tid];
    rvd[tid] = rvv;
    rvd[512 + tid] = rvv;
    __syncthreads();
    float a0 = 0.f, a1 = 0.f, a2 = 0.f, a3 = 0.f;
    if (tt == 2) {
      const int jb = jq << 7;
#pragma unroll 8
      for (int jj = 0; jj < 128; jj += 4) {
        const int j = jb + jj;
        const float4 l4 = *(const float4*)&lv[j];
        const float4 r0 = *(const float4*)&rvd[j + k4];
        const float4 r1 = *(const float4*)&rvd[j + k4 + 4];
        a0 += l4.x * r0.x + l4.y * r0.y + l4.z * r0.z + l4.w * r0.w;
        a1 += l4.x * r0.y + l4.y * r0.z + l4.z * r0.w + l4.w * r1.x;
        a2 += l4.x * r0.z + l4.y * r0.w + l4.z * r1.x + l4.w * r1.y;
        a3 += l4.x * r0.w + l4.y * r1.x + l4.z * r1.y + l4.w * r1.z;
      }
    }
    cpart[jq][k4 + 0] = a0; cpart[jq][k4 + 1] = a1;
    cpart[jq][k4 + 2] = a2; cpart[jq][k4 + 3] = a3;
    __syncthreads();
    const float ck = cpart[0][tid] + cpart[1][tid] + cpart[2][tid] + cpart[3][tid];
    float ss = ck * ck;
#pragma unroll
    for (int off = 32; off; off >>= 1) ss += __shfl_down(ss, off);
    if (lane == 0) red[wid] = ss;
    __syncthreads();
    if (tid == 0) {
      float tot = 0.f;
#pragma unroll
      for (int w = 0; w < 8; ++w) tot += red[w];
      red[8] = 1.f / fmaxf(sqrtf(tot), 1e-12f);
    }
    __syncthreads();
    if (tt == 2) {
      vb[(size_t)p * NH + tid] = ck * red[8];
    } else if (tt == 1) {
      vb[(size_t)p * NH + tid] = lv[tid];
    }
    __syncthreads();
  }
}

// ---------------- K6: output GEMMs (word / phrase) ------------------------
template <int MODE>
__global__ __launch_bounds__(256) void k_out(
    const float* __restrict__ vec, const float* __restrict__ W,
    const float* __restrict__ bias, float* __restrict__ out) {
  constexpr int NOUT = MODE ? NPV : NWV;
  __shared__ float As[16][68], Bs[16][68];
  const int tid = threadIdx.x;
  const int n0 = blockIdx.x * 64, m0 = blockIdx.y * 64;
  const int lr = tid >> 2, lc4 = (tid & 3) << 2;
  const int tx = tid & 15, ty = tid >> 4;
  const int m = m0 + lr;
  int vr;
  if (MODE == 0) {
    vr = (m >> 7) * NTOT + (m & 127);
  } else {
    const int bb = m / 127;
    vr = bb * NTOT + NS + (m - bb * 127);
  }
  const float* arow = vec + (size_t)vr * NH;
  const int n = n0 + lr;
  const float* brow = W + (size_t)n * NH;
  const bool bok = (n < NOUT);
  float acc[4][4] = {};
  for (int k0 = 0; k0 < NH; k0 += 16) {
    const float4 a4 = *(const float4*)(arow + k0 + lc4);
    As[lc4 + 0][lr] = a4.x; As[lc4 + 1][lr] = a4.y;
    As[lc4 + 2][lr] = a4.z; As[lc4 + 3][lr] = a4.w;
    float4 b4 = make_float4(0.f, 0.f, 0.f, 0.f);
    if (bok) b4 = *(const float4*)(brow + k0 + lc4);
    Bs[lc4 + 0][lr] = b4.x; Bs[lc4 + 1][lr] = b4.y;
    Bs[lc4 + 2][lr] = b4.z; Bs[lc4 + 3][lr] = b4.w;
    __syncthreads();
#pragma unroll
    for (int kk = 0; kk < 16; ++kk) {
      const float4 av = *(const float4*)&As[kk][ty << 2];
      const float4 bv = *(const float4*)&Bs[kk][tx << 2];
      FMA4x4(acc, av, bv)
    }
    __syncthreads();
  }
#pragma unroll
  for (int i = 0; i < 4; ++i)
#pragma unroll
    for (int j = 0; j < 4; ++j) {
      const int nn = n0 + (tx << 2) + j;
      if (nn < NOUT)
        out[(size_t)(m0 + (ty << 2) + i) * NOUT + nn] = acc[i][j] + bias[nn];
    }
}

// ---------------- K7: labels (int32 -> f32 copy) --------------------------
__global__ __launch_bounds__(256) void k_labels(
    const int* __restrict__ lab, float* __restrict__ outw,
    float* __restrict__ outp) {
  const int i = blockIdx.x * 256 + threadIdx.x;
  if (i < NB * NS) {
    const int b = i >> 7, s = i & 127;
    outw[i] = (float)lab[b * NTOT + s];
  }
  if (i < NB * NSTEPS) {
    const int b = i / 127;
    outp[i] = (float)lab[b * NTOT + NS + (i - b * 127)];
  }
}

extern "C" void kernel_launch(void* const* d_in, const int* in_sizes, int n_in,
                              void* d_out, int out_size, void* d_ws, size_t ws_size,
                              hipStream_t stream) {
  (void)in_sizes; (void)n_in; (void)out_size; (void)ws_size;
  const float* elmo     = (const float*)d_in[0];
  const float* w_ih_f   = (const float*)d_in[1];
  const float* w_hh_f   = (const float*)d_in[2];
  const float* b_f      = (const float*)d_in[3];
  const float* w_ih_b   = (const float*)d_in[4];
  const float* w_hh_b   = (const float*)d_in[5];
  const float* b_b      = (const float*)d_in[6];
  const float* W1       = (const float*)d_in[7];
  const float* W2       = (const float*)d_in[8];
  const float* word_W   = (const float*)d_in[9];
  const float* word_b   = (const float*)d_in[10];
  const float* phrase_W = (const float*)d_in[11];
  const float* phrase_b = (const float*)d_in[12];
  const int* cinfo      = (const int*)d_in[13];
  const int* lab        = (const int*)d_in[15];

  float* ws    = (float*)d_ws;
  float* xp    = ws;
  float* h_all = xp + XP_SZ;
  float* vec   = h_all + H_SZ;
  unsigned short* h_bf = (unsigned short*)(vec + VEC_SZ);
  int* bar     = (int*)(h_bf + HB_SZ);

  float* out_word = (float*)d_out;                       // 8192 x 511
  float* out_phr  = out_word + (size_t)8192 * NWV;       // 8128 x 152
  float* out_lw   = out_phr + (size_t)8128 * NPV;        // 8192
  float* out_lp   = out_lw + 8192;                       // 8128

  k_xp<<<dim3(64, 128), 256, 0, stream>>>(elmo, w_ih_f, w_ih_b, b_f, b_b, xp, bar);
  k_lstm<<<dim3(64), 256, 0, stream>>>(w_hh_f, w_hh_b, xp, h_all, h_bf, bar);
  k_comb<<<dim3(8, 128), 256, 0, stream>>>(h_all, W1, W2, vec);
  k_norm<<<dim3(2048), 256, 0, stream>>>(vec);
  k_compose<<<dim3(64), 512, 0, stream>>>(vec, cinfo);
  k_out<0><<<dim3(8, 128), 256, 0, stream>>>(vec, word_W, word_b, out_word);
  k_out<1><<<dim3(3, 127), 256, 0, stream>>>(vec, phrase_W, phrase_b, out_phr);
  k_labels<<<dim3(32), 256, 0, stream>>>(lab, out_lw, out_lp);
}